// Round 3
// baseline (436.320 us; speedup 1.0000x reference)
//
#include <hip/hip_runtime.h>
#include <hip/hip_bf16.h>

#define TQn 1024
#define NB  16
#define DIM 1024
#define BM  128
#define BN  128
#define BK  32
#define STR 40     // padded bf16 LDS row stride
#define VSTR 132   // padded fp32 LDS row stride for values tile

typedef __attribute__((ext_vector_type(4))) float f32x4;
typedef __attribute__((ext_vector_type(8))) short s16x8;
typedef __attribute__((ext_vector_type(4))) short s16x4;

__device__ __forceinline__ short f2bf(float f){
  union { float f; unsigned u; } v; v.f = f;
  unsigned r = v.u + 0x7fffu + ((v.u >> 16) & 1u);  // RNE
  return (short)(r >> 16);
}
__device__ __forceinline__ float bf2f(short h){
  union { unsigned u; float f; } v; v.u = ((unsigned)(unsigned short)h) << 16;
  return v.f;
}

// K1: qp[m][k] = sum_q query[m][q] * W[k][q]  (m = t*16+b). Hi/lo split on BOTH
// operands, 3 MFMA chains -> qp error ~ fp32-accum only.
__global__ __launch_bounds__(256) void k1_qp(const float* __restrict__ A,
                                             const float* __restrict__ Wm,
                                             float* __restrict__ C){
  __shared__ __align__(16) short Ah[BM * STR];
  __shared__ __align__(16) short Al[BM * STR];
  __shared__ __align__(16) short Bh[BN * STR];
  __shared__ __align__(16) short Bl[BN * STR];
  const int tid = threadIdx.x;
  const int m0 = blockIdx.y * BM, n0 = blockIdx.x * BN;
  const int lane = tid & 63, wid = tid >> 6;
  const int wm = (wid >> 1) * 64, wn = (wid & 1) * 64;
  const int cl = lane & 15, kg = lane >> 4;
  const int rr = tid >> 3, f4 = (tid & 7) * 4;
  f32x4 acc[4][4] = {};
  for (int k0 = 0; k0 < DIM; k0 += BK){
    #pragma unroll
    for (int i = 0; i < 4; ++i){
      const int r = rr + i * 32;
      f32x4 va = *reinterpret_cast<const f32x4*>(A  + (size_t)(m0 + r) * DIM + k0 + f4);
      f32x4 vb = *reinterpret_cast<const f32x4*>(Wm + (size_t)(n0 + r) * DIM + k0 + f4);
      s16x4 ha, la, hb, lb;
      #pragma unroll
      for (int j = 0; j < 4; ++j){
        ha[j] = f2bf(va[j]); la[j] = f2bf(va[j] - bf2f(ha[j]));
        hb[j] = f2bf(vb[j]); lb[j] = f2bf(vb[j] - bf2f(hb[j]));
      }
      *reinterpret_cast<s16x4*>(&Ah[r * STR + f4]) = ha;
      *reinterpret_cast<s16x4*>(&Al[r * STR + f4]) = la;
      *reinterpret_cast<s16x4*>(&Bh[r * STR + f4]) = hb;
      *reinterpret_cast<s16x4*>(&Bl[r * STR + f4]) = lb;
    }
    __syncthreads();
    s16x8 ah[4], al8[4], bh8[4], bl8[4];
    #pragma unroll
    for (int m = 0; m < 4; ++m){
      ah[m]  = *reinterpret_cast<const s16x8*>(&Ah[(wm + m * 16 + cl) * STR + kg * 8]);
      al8[m] = *reinterpret_cast<const s16x8*>(&Al[(wm + m * 16 + cl) * STR + kg * 8]);
    }
    #pragma unroll
    for (int n = 0; n < 4; ++n){
      bh8[n] = *reinterpret_cast<const s16x8*>(&Bh[(wn + n * 16 + cl) * STR + kg * 8]);
      bl8[n] = *reinterpret_cast<const s16x8*>(&Bl[(wn + n * 16 + cl) * STR + kg * 8]);
    }
    #pragma unroll
    for (int m = 0; m < 4; ++m)
      #pragma unroll
      for (int n = 0; n < 4; ++n){
        acc[m][n] = __builtin_amdgcn_mfma_f32_16x16x32_bf16(ah[m],  bh8[n], acc[m][n], 0, 0, 0);
        acc[m][n] = __builtin_amdgcn_mfma_f32_16x16x32_bf16(al8[m], bh8[n], acc[m][n], 0, 0, 0);
        acc[m][n] = __builtin_amdgcn_mfma_f32_16x16x32_bf16(ah[m],  bl8[n], acc[m][n], 0, 0, 0);
      }
    __syncthreads();
  }
  #pragma unroll
  for (int m = 0; m < 4; ++m){
    const int row = m0 + wm + m * 16 + kg * 4;
    #pragma unroll
    for (int n = 0; n < 4; ++n){
      const int col = n0 + wn + n * 16 + cl;
      #pragma unroll
      for (int j = 0; j < 4; ++j)
        C[(size_t)(row + j) * DIM + col] = acc[m][n][j];
    }
  }
}

// K2: logits[b][t][s] = sum_d qp[t*16+b][d] * keys[b][s][d]; hi/lo split on BOTH sides
__global__ __launch_bounds__(256) void k2_logits(const float* __restrict__ qp,
                                                 const float* __restrict__ keys,
                                                 float* __restrict__ out){
  __shared__ __align__(16) short Ah[BM * STR];
  __shared__ __align__(16) short Al[BM * STR];
  __shared__ __align__(16) short Bh[BN * STR];
  __shared__ __align__(16) short Bl[BN * STR];
  const int tid = threadIdx.x;
  const int b = blockIdx.z;
  const int t0 = blockIdx.y * BM, s0 = blockIdx.x * BN;
  const int lane = tid & 63, wid = tid >> 6;
  const int wm = (wid >> 1) * 64, wn = (wid & 1) * 64;
  const int cl = lane & 15, kg = lane >> 4;
  const int rr = tid >> 3, f4 = (tid & 7) * 4;
  f32x4 acc[4][4] = {};
  for (int k0 = 0; k0 < DIM; k0 += BK){
    #pragma unroll
    for (int i = 0; i < 4; ++i){
      const int r = rr + i * 32;
      f32x4 va = *reinterpret_cast<const f32x4*>(qp   + (size_t)((t0 + r) * NB + b) * DIM + k0 + f4);
      f32x4 vb = *reinterpret_cast<const f32x4*>(keys + ((size_t)b * DIM + s0 + r) * DIM + k0 + f4);
      s16x4 ha, la, hb, lb;
      #pragma unroll
      for (int j = 0; j < 4; ++j){
        ha[j] = f2bf(va[j]); la[j] = f2bf(va[j] - bf2f(ha[j]));
        hb[j] = f2bf(vb[j]); lb[j] = f2bf(vb[j] - bf2f(hb[j]));
      }
      *reinterpret_cast<s16x4*>(&Ah[r * STR + f4]) = ha;
      *reinterpret_cast<s16x4*>(&Al[r * STR + f4]) = la;
      *reinterpret_cast<s16x4*>(&Bh[r * STR + f4]) = hb;
      *reinterpret_cast<s16x4*>(&Bl[r * STR + f4]) = lb;
    }
    __syncthreads();
    s16x8 ah[4], al8[4], bh8[4], bl8[4];
    #pragma unroll
    for (int m = 0; m < 4; ++m){
      ah[m]  = *reinterpret_cast<const s16x8*>(&Ah[(wm + m * 16 + cl) * STR + kg * 8]);
      al8[m] = *reinterpret_cast<const s16x8*>(&Al[(wm + m * 16 + cl) * STR + kg * 8]);
    }
    #pragma unroll
    for (int n = 0; n < 4; ++n){
      bh8[n] = *reinterpret_cast<const s16x8*>(&Bh[(wn + n * 16 + cl) * STR + kg * 8]);
      bl8[n] = *reinterpret_cast<const s16x8*>(&Bl[(wn + n * 16 + cl) * STR + kg * 8]);
    }
    #pragma unroll
    for (int m = 0; m < 4; ++m)
      #pragma unroll
      for (int n = 0; n < 4; ++n){
        acc[m][n] = __builtin_amdgcn_mfma_f32_16x16x32_bf16(ah[m],  bh8[n], acc[m][n], 0, 0, 0);
        acc[m][n] = __builtin_amdgcn_mfma_f32_16x16x32_bf16(al8[m], bh8[n], acc[m][n], 0, 0, 0);
        acc[m][n] = __builtin_amdgcn_mfma_f32_16x16x32_bf16(ah[m],  bl8[n], acc[m][n], 0, 0, 0);
      }
    __syncthreads();
  }
  #pragma unroll
  for (int m = 0; m < 4; ++m){
    const int trow = t0 + wm + m * 16 + kg * 4;
    #pragma unroll
    for (int n = 0; n < 4; ++n){
      const int scol = s0 + wn + n * 16 + cl;
      #pragma unroll
      for (int j = 0; j < 4; ++j)
        out[((size_t)b * TQn + trow + j) * DIM + scol] = acc[m][n][j];
    }
  }
}

// K3: in-place row softmax of (logits + mask[b][s]) over s
__global__ __launch_bounds__(256) void k3_softmax(float* __restrict__ logits,
                                                  const float* __restrict__ mask){
  const int row = blockIdx.x;       // b*TQ + t
  const int b = row >> 10;
  const int tid = threadIdx.x;
  float* p = logits + (size_t)row * DIM;
  f32x4 v  = *reinterpret_cast<const f32x4*>(p + tid * 4);
  f32x4 mk = *reinterpret_cast<const f32x4*>(mask + (size_t)b * DIM + tid * 4);
  v = v + mk;
  float mx = fmaxf(fmaxf(v[0], v[1]), fmaxf(v[2], v[3]));
  #pragma unroll
  for (int off = 32; off; off >>= 1) mx = fmaxf(mx, __shfl_xor(mx, off));
  __shared__ float red[8];
  const int lane = tid & 63, wid = tid >> 6;
  if (lane == 0) red[wid] = mx;
  __syncthreads();
  mx = fmaxf(fmaxf(red[0], red[1]), fmaxf(red[2], red[3]));
  f32x4 e;
  #pragma unroll
  for (int j = 0; j < 4; ++j) e[j] = __expf(v[j] - mx);
  float s = e[0] + e[1] + e[2] + e[3];
  #pragma unroll
  for (int off = 32; off; off >>= 1) s += __shfl_xor(s, off);
  if (lane == 0) red[4 + wid] = s;
  __syncthreads();
  s = red[4] + red[5] + red[6] + red[7];
  const float inv = 1.0f / s;
  f32x4 o;
  #pragma unroll
  for (int j = 0; j < 4; ++j) o[j] = e[j] * inv;
  *reinterpret_cast<f32x4*>(p + tid * 4) = o;
}

// K4: ctx[b][t][v] = sum_s score[b][t][s] * values[b][s][v]
__global__ __launch_bounds__(256) void k4_ctx(const float* __restrict__ score,
                                              const float* __restrict__ values,
                                              float* __restrict__ ctx){
  __shared__ __align__(16) short As[BM * STR];
  __shared__ __align__(16) float Vs[BK * VSTR];
  const int tid = threadIdx.x;
  const int b = blockIdx.z;
  const int t0 = blockIdx.y * BM, v0 = blockIdx.x * BN;
  const int lane = tid & 63, wid = tid >> 6;
  const int wm = (wid >> 1) * 64, wn = (wid & 1) * 64;
  const int cl = lane & 15, kg = lane >> 4;
  const int rr = tid >> 3, f4 = (tid & 7) * 4;
  const int vr = tid >> 5, vc = tid & 31;
  f32x4 acc[4][4] = {};
  for (int k0 = 0; k0 < DIM; k0 += BK){
    #pragma unroll
    for (int i = 0; i < 4; ++i){
      const int r = rr + i * 32;
      f32x4 va = *reinterpret_cast<const f32x4*>(score + ((size_t)b * TQn + t0 + r) * DIM + k0 + f4);
      s16x4 ha;
      #pragma unroll
      for (int j = 0; j < 4; ++j) ha[j] = f2bf(va[j]);
      *reinterpret_cast<s16x4*>(&As[r * STR + f4]) = ha;
      const int vrow = vr + i * 8;
      f32x4 vv = *reinterpret_cast<const f32x4*>(values + ((size_t)b * DIM + k0 + vrow) * DIM + v0 + vc * 4);
      const int cb = vc ^ (((vrow >> 3) & 1) << 2);
      *reinterpret_cast<f32x4*>(&Vs[vrow * VSTR + cb * 4]) = vv;
    }
    __syncthreads();
    s16x8 af[4], bfr[4];
    #pragma unroll
    for (int m = 0; m < 4; ++m)
      af[m] = *reinterpret_cast<const s16x8*>(&As[(wm + m * 16 + cl) * STR + kg * 8]);
    #pragma unroll
    for (int n = 0; n < 4; ++n){
      const int colb = wn + n * 16 + cl;
      const int cb = (colb >> 2) ^ ((kg & 1) << 2);
      #pragma unroll
      for (int j = 0; j < 8; ++j){
        const int rowv = kg * 8 + j;
        bfr[n][j] = f2bf(Vs[rowv * VSTR + cb * 4 + (colb & 3)]);
      }
    }
    #pragma unroll
    for (int m = 0; m < 4; ++m)
      #pragma unroll
      for (int n = 0; n < 4; ++n)
        acc[m][n] = __builtin_amdgcn_mfma_f32_16x16x32_bf16(af[m], bfr[n], acc[m][n], 0, 0, 0);
    __syncthreads();
  }
  #pragma unroll
  for (int m = 0; m < 4; ++m){
    const int trow = t0 + wm + m * 16 + kg * 4;
    #pragma unroll
    for (int n = 0; n < 4; ++n){
      const int vcol = v0 + wn + n * 16 + cl;
      #pragma unroll
      for (int j = 0; j < 4; ++j)
        ctx[((size_t)b * TQn + trow + j) * DIM + vcol] = acc[m][n][j];
    }
  }
}

extern "C" void kernel_launch(void* const* d_in, const int* in_sizes, int n_in,
                              void* d_out, int out_size, void* d_ws, size_t ws_size,
                              hipStream_t stream){
  (void)in_sizes; (void)n_in; (void)out_size; (void)d_ws; (void)ws_size;
  const float* query  = (const float*)d_in[0];  // [1024][16][1024]
  const float* keys   = (const float*)d_in[1];  // [16][1024][1024]
  const float* values = (const float*)d_in[2];  // [16][1024][1024]
  const float* mask   = (const float*)d_in[3];  // [16][1024]
  const float* Wm     = (const float*)d_in[4];  // [1024][1024]
  float* score = (float*)d_out;                              // [16][1024][1024]
  float* ctx   = score + (size_t)NB * TQn * DIM;             // also qp scratch [16384][1024]
  dim3 blk(256, 1, 1);
  k1_qp<<<dim3(DIM / BN, (TQn * NB) / BM, 1), blk, 0, stream>>>(query, Wm, ctx);
  k2_logits<<<dim3(DIM / BN, TQn / BM, NB), blk, 0, stream>>>(ctx, keys, score);
  k3_softmax<<<dim3(NB * TQn, 1, 1), blk, 0, stream>>>(score, mask);
  k4_ctx<<<dim3(DIM / BN, TQn / BM, NB), blk, 0, stream>>>(score, values, ctx);
}